// Round 13
// baseline (205.674 us; speedup 1.0000x reference)
//
#include <hip/hip_runtime.h>
#include <hip/hip_bf16.h>

#define LARGE_F 1e30f
#define LOG2E_F 1.4426950408889634f
#define LN2_F   0.6931471805599453f

constexpr int BB = 128;
constexpr int NN = 512;
constexpr int MM = 512;
constexpr int KK = 64;
// D layout: bf16, offset = 512*i + p  (p = i+j). Row i occupies [513i, 513i+511].
constexpr int PBATCH = 262656;              // shorts per batch (525,312 B, 16B-aligned)
constexpr size_t NEED = (size_t)BB * PBATCH * 2 + 4096;  // + slop for band-64 overshoot

// lane i <- lane i-1 via DPP wave_shr:1 (VALU). Lane 0 receives `bound`.
__device__ __forceinline__ float wave_shr1(float v, float bound) {
    const int r = __builtin_amdgcn_update_dpp(__float_as_int(bound), __float_as_int(v),
                                              0x138, 0xf, 0xf, false);
    return __int_as_float(r);
}

// ---------------- Phase 1: D[i][p] = ||x_i - y_j||^2 * log2e  (bf16, p=i+j).
// 128x128 tile, 8x8 microtile. Epilogue stages bf16 tile in LDS, then per-row
// contiguous b16 stores. (unchanged from round 12)
__global__ __launch_bounds__(256, 2) void sdtw_dist(const float* __restrict__ x,
                                                    const float* __restrict__ y,
                                                    unsigned short* __restrict__ Dws) {
    __shared__ __align__(16) float xs[128][68];
    __shared__ __align__(16) float ys[128][68];
    __shared__ float x2s[128];
    __shared__ float y2s[128];
    unsigned short (*dt)[132] = (unsigned short (*)[132])(&xs[0][0]);  // 33792B

    const int b  = blockIdx.y;
    const int ti = (blockIdx.x >> 2) << 7;
    const int tj = (blockIdx.x & 3) << 7;
    const int t  = threadIdx.x;

    const float* xb = x + ((size_t)b * NN + ti) * KK;
    const float* yb = y + ((size_t)b * MM + tj) * KK;

    {   // stage 128x64 tiles (coalesced float4)
        const int r0 = t >> 4;
        const int c0 = (t & 15) << 2;
#pragma unroll
        for (int q = 0; q < 8; ++q) {
            const int r = r0 + (q << 4);
            *(float4*)(&xs[r][c0]) = *(const float4*)(xb + r * KK + c0);
            *(float4*)(&ys[r][c0]) = *(const float4*)(yb + r * KK + c0);
        }
    }
    __syncthreads();

    {   // row squared norms
        const int r = t & 127;
        const float* row = (t < 128) ? &xs[r][0] : &ys[r][0];
        float s = 0.f;
#pragma unroll
        for (int k = 0; k < KK; k += 4) {
            const float4 v = *(const float4*)(row + k);
            s = fmaf(v.x, v.x, s); s = fmaf(v.y, v.y, s);
            s = fmaf(v.z, v.z, s); s = fmaf(v.w, v.w, s);
        }
        if (t < 128) x2s[r] = s; else y2s[r] = s;
    }
    __syncthreads();

    const int ty = t >> 4;   // 0..15
    const int tx = t & 15;   // 0..15

    float acc[8][8] = {};
    for (int k0 = 0; k0 < KK; k0 += 4) {
        float4 xa[8], yv[8];
#pragma unroll
        for (int a = 0; a < 8; ++a) xa[a] = *(const float4*)(&xs[(a << 4) + ty][k0]);
#pragma unroll
        for (int c = 0; c < 8; ++c) yv[c] = *(const float4*)(&ys[(c << 4) + tx][k0]);
#pragma unroll
        for (int a = 0; a < 8; ++a) {
#pragma unroll
            for (int c = 0; c < 8; ++c) {
                acc[a][c] = fmaf(xa[a].x, yv[c].x, acc[a][c]);
                acc[a][c] = fmaf(xa[a].y, yv[c].y, acc[a][c]);
                acc[a][c] = fmaf(xa[a].z, yv[c].z, acc[a][c]);
                acc[a][c] = fmaf(xa[a].w, yv[c].w, acc[a][c]);
            }
        }
    }
    __syncthreads();   // xs dead -> alias as dt

#pragma unroll
    for (int a = 0; a < 8; ++a) {
        const float xx = x2s[(a << 4) + ty];
#pragma unroll
        for (int c = 0; c < 8; ++c) {
            const float d = (xx + y2s[(c << 4) + tx] - 2.f * acc[a][c]) * LOG2E_F;
            __hip_bfloat16 h = __float2bfloat16(d);
            dt[(a << 4) + ty][(c << 4) + tx] = *(unsigned short*)&h;
        }
    }
    __syncthreads();

    {   // write-out: row r -> D[gi][gi+tj .. +127]: contiguous 128 shorts.
        const int wv = t >> 6, lane = t & 63;
        unsigned short* Dg = Dws + (size_t)b * PBATCH;
#pragma unroll 4
        for (int r = wv; r < 128; r += 4) {
            const int gi = ti + r;
            const int base = 512 * gi + (gi + tj);
            Dg[base + lane]      = dt[r][lane];
            Dg[base + lane + 64] = dt[r][lane + 64];
        }
    }
}

// ---------------- Phase 2: band-pipelined DP, 512 threads (8 waves = 2/SIMD),
// thread tid owns row tid. Wave wv does 16-diag band k at epoch e = wv + k;
// one raw barrier per epoch (71 total). Round-13 changes vs round 12:
//  (a) boundary readlanes hoisted to band start (out of the per-step chain),
//  (b) h exported in float4 chunks every 4 steps (live h = 4 regs, kills the
//      h[16] scratch spill that VGPR=24 betrayed),
//  (c) band prefetch unchanged (c0/c1 + sched_barrier(0)), now with headroom.
__global__ __launch_bounds__(512, 1) void sdtw_dp(const unsigned short* __restrict__ Dws,
                                                  float* __restrict__ out) {
    __shared__ __align__(16) float hnd[3][8][16];
    const int b    = blockIdx.x;
    const int tid  = threadIdx.x;        // row
    const int lane = tid & 63;
    const int wv   = tid >> 6;

    if (tid < 384) ((float*)hnd)[tid] = LARGE_F;
    __syncthreads();

    const char* Dbase = (const char*)Dws;
    unsigned off = (unsigned)b * 525312u + (unsigned)tid * 1024u;  // row tid, band 0

    float cur = LARGE_F;                     // R_{p-1}[tid]
    float nw  = (tid == 0) ? 0.f : LARGE_F;  // R_{p-2}[tid-1]; corner (0,0)=0
    float res = 0.f;
    float hband_prev = LARGE_F;
    const bool haveup = (wv > 0);
    const bool sel    = haveup && (lane == 0);

    uint4 c0 = *(const uint4*)(Dbase + off);
    uint4 c1 = *(const uint4*)(Dbase + off + 16);
    off += 32;

    int m0 = 0, m1 = 2;                      // e%3, (e-1)%3
#pragma unroll 1
    for (int e = 0; e < 71; ++e) {
        const int k = e - wv;
        if (0 <= k && k < 64) {
            // Current band -> q regs; prefetch band k+1 into c0/c1.
            const unsigned q[8] = {c0.x, c0.y, c0.z, c0.w, c1.x, c1.y, c1.z, c1.w};
            c0 = *(const uint4*)(Dbase + off);       // k=63 overshoots into slop
            c1 = *(const uint4*)(Dbase + off + 16);
            off += 32;
            __builtin_amdgcn_sched_barrier(0);       // pin loads before compute

            // Boundary row (64wv-1) values, hoisted out of the step chain.
            const float hband = haveup ? hnd[m1][wv - 1][lane & 15] : LARGE_F;
            float hu[16];
            hu[0] = __int_as_float(
                __builtin_amdgcn_readlane(__float_as_int(hband_prev), 15));
#pragma unroll
            for (int u = 1; u < 16; ++u)
                hu[u] = __int_as_float(
                    __builtin_amdgcn_readlane(__float_as_int(hband), u - 1));
            hband_prev = hband;

#pragma unroll
            for (int u4 = 0; u4 < 4; ++u4) {
                float hq[4];
#pragma unroll
                for (int v = 0; v < 4; ++v) {
                    const int u = (u4 << 2) + v;
                    const unsigned wq = q[u >> 1];
                    const float d = __uint_as_float(
                        (u & 1) ? (wq & 0xffff0000u) : (wq << 16));
                    const float nvec = wave_shr1(cur, LARGE_F);
                    const float n  = sel ? hu[u] : nvec;
                    const float mn = fminf(fminf(cur, n), nw);
                    const float mx = fmaxf(fmaxf(cur, n), nw);
                    const float md = __builtin_amdgcn_fmed3f(cur, n, nw);
                    const float sm = mn - log2f(1.f + exp2f(mn - md) + exp2f(mn - mx));
                    const float newc = d + sm;
                    hq[v] = newc;
                    if (u == 14) { if (k == 63) res = newc; }   // cell (511,511)
                    nw = n; cur = newc;
                }
                if (lane == 63)
                    *(float4*)(&hnd[m0][wv][u4 << 2]) =
                        make_float4(hq[0], hq[1], hq[2], hq[3]);
            }
        }
        // Epoch barrier: LDS visibility only; vmcnt NOT drained.
        asm volatile("s_waitcnt lgkmcnt(0)" ::: "memory");
        __builtin_amdgcn_s_barrier();
        m0 = (m0 == 2) ? 0 : m0 + 1;
        m1 = (m1 == 2) ? 0 : m1 + 1;
    }
    if (tid == 511) out[b] = res * LN2_F;
}

// ---------------- Fallback (only if ws too small): fused, correct, slow.
__global__ __launch_bounds__(512) void sdtw_fused_naive(const float* __restrict__ x,
                                                        const float* __restrict__ y,
                                                        float* __restrict__ out) {
    __shared__ float rbuf[3][NN];
    __shared__ float y2s[MM];
    const int b = blockIdx.x;
    const int i = threadIdx.x;

    const float* xrow  = x + ((size_t)b * NN + i) * KK;
    const float* ybase = y + (size_t)b * MM * KK;

    float xr[KK];
    float x2 = 0.f;
#pragma unroll
    for (int k = 0; k < KK; k += 4) {
        const float4 v = *(const float4*)(xrow + k);
        xr[k] = v.x; xr[k + 1] = v.y; xr[k + 2] = v.z; xr[k + 3] = v.w;
        x2 = fmaf(v.x, v.x, fmaf(v.y, v.y, fmaf(v.z, v.z, fmaf(v.w, v.w, x2))));
    }
    {
        const float* yrow = ybase + (size_t)i * KK;
        float s = 0.f;
#pragma unroll
        for (int k = 0; k < KK; k += 4) {
            const float4 v = *(const float4*)(yrow + k);
            s = fmaf(v.x, v.x, s); s = fmaf(v.y, v.y, s);
            s = fmaf(v.z, v.z, s); s = fmaf(v.w, v.w, s);
        }
        y2s[i] = s;
    }
    rbuf[0][i] = LARGE_F;
    rbuf[1][i] = LARGE_F;
    rbuf[2][i] = LARGE_F;

    float* row_w  = rbuf[0];
    float* row_p  = rbuf[2];
    float* row_p2 = rbuf[1];
    __syncthreads();

    float cur = LARGE_F;
    for (int p = 0; p < NN + MM - 1; ++p) {
        const int j0 = p - i;
        const bool valid = (j0 >= 0) && (j0 < MM);
        float dg = 0.f;
        if (valid) {
            const float* yrow = ybase + (size_t)j0 * KK;
            float dot = 0.f;
#pragma unroll
            for (int k = 0; k < KK; k += 4) {
                const float4 v = *(const float4*)(yrow + k);
                dot = fmaf(xr[k], v.x, dot);
                dot = fmaf(xr[k + 1], v.y, dot);
                dot = fmaf(xr[k + 2], v.z, dot);
                dot = fmaf(xr[k + 3], v.w, dot);
            }
            dg = x2 + y2s[j0] - 2.f * dot;
        }
        const float r_w  = row_p[i];
        const float r_n  = (i > 0) ? row_p[i - 1] : LARGE_F;
        const float r_nw = (i > 0) ? row_p2[i - 1] : ((p == 0) ? 0.f : LARGE_F);

        const float m = fminf(fminf(r_nw, r_n), r_w);
        const float s = __expf(m - r_nw) + __expf(m - r_n) + __expf(m - r_w);
        const float softmin = m - __logf(s);

        cur = valid ? (dg + softmin) : LARGE_F;
        row_w[i] = cur;
        __syncthreads();

        float* tmp = row_w;
        row_w = row_p2; row_p2 = row_p; row_p = tmp;
    }
    if (i == NN - 1) out[b] = cur;
}

extern "C" void kernel_launch(void* const* d_in, const int* in_sizes, int n_in,
                              void* d_out, int out_size, void* d_ws, size_t ws_size,
                              hipStream_t stream) {
    const float* x = (const float*)d_in[0];
    const float* y = (const float*)d_in[1];
    float* out = (float*)d_out;

    if (ws_size >= NEED) {   // 67,244,032 B
        unsigned short* Dws = (unsigned short*)d_ws;
        sdtw_dist<<<dim3(16, BB), 256, 0, stream>>>(x, y, Dws);
        sdtw_dp<<<dim3(BB), 512, 0, stream>>>(Dws, out);
    } else {
        sdtw_fused_naive<<<dim3(BB), 512, 0, stream>>>(x, y, out);
    }
}

// Round 14
// 164.787 us; speedup vs baseline: 1.2481x; 1.2481x over previous
//
#include <hip/hip_runtime.h>
#include <hip/hip_bf16.h>

#define LARGE_F 1e30f
#define LOG2E_F 1.4426950408889634f
#define LN2_F   0.6931471805599453f

constexpr int BB = 128;
constexpr int NN = 512;
constexpr int MM = 512;
constexpr int KK = 64;
// D layout: bf16, short index = 512*i + p (p = i+j). Row i spans [513i, 513i+511].
constexpr int PBATCH = 262656;              // shorts per batch (525,312 B)
constexpr size_t NEED = (size_t)BB * PBATCH * 2 + 4096;  // + band-64 overshoot slop

typedef __attribute__((ext_vector_type(8))) short short8;   // 8 bf16 (guide §3)
typedef __attribute__((ext_vector_type(4))) float f32x4;

// lane i <- lane i-1 via DPP wave_shr:1 (VALU). Lane 0 receives `bound`.
__device__ __forceinline__ float wave_shr1(float v, float bound) {
    const int r = __builtin_amdgcn_update_dpp(__float_as_int(bound), __float_as_int(v),
                                              0x138, 0xf, 0xf, false);
    return __int_as_float(r);
}

__device__ __forceinline__ unsigned pack_bf16(float a, float b) {
    __hip_bfloat16 ha = __float2bfloat16(a);
    __hip_bfloat16 hb = __float2bfloat16(b);
    return (unsigned)*(unsigned short*)&ha | ((unsigned)*(unsigned short*)&hb << 16);
}

// ---------------- Phase 1 (MFMA): D[i][p] = ||x_i - y_j||^2 * log2e (bf16).
// G = X·Y^T via mfma_f32_16x16x32_bf16; x2/y2 from original f32. 128x128 tile,
// 4 waves (each a 64x64 quadrant). XCD swizzle: batch b's 16 tiles -> XCD b%8.
__global__ __launch_bounds__(256, 2) void sdtw_dist(const float* __restrict__ x,
                                                    const float* __restrict__ y,
                                                    unsigned short* __restrict__ Dws) {
    __shared__ __align__(16) unsigned short xbf[128][88];   // stride 88: 2-way banks
    __shared__ __align__(16) unsigned short ybf[128][88];
    __shared__ float x2s[128], y2s[128];
    __shared__ float xpart[128][2], ypart[128][2];
    unsigned short (*dt)[132] = (unsigned short (*)[132])(&xbf[0][0]);  // 33792B<=45056B

    const int bid  = blockIdx.x;               // 0..2047
    const int xcd  = bid & 7, sidx = bid >> 3;
    const int g    = sidx >> 4, tile = sidx & 15;
    const int b    = xcd + (g << 3);           // batch: tiles of b all on XCD b%8
    const int ti   = (tile >> 2) << 7, tj = (tile & 3) << 7;
    const int t    = threadIdx.x;

    const float* xb = x + ((size_t)b * NN + ti) * KK;
    const float* yb = y + ((size_t)b * MM + tj) * KK;

    {   // stage f32 -> bf16 LDS + f32 partial squared norms
        const int r = t >> 1, h = t & 1;
        const float* xr = xb + r * KK + h * 32;
        const float* yr = yb + r * KK + h * 32;
        float sx = 0.f, sy = 0.f;
        unsigned xu[16], yu[16];
#pragma unroll
        for (int q = 0; q < 8; ++q) {
            const float4 v = *(const float4*)(xr + 4 * q);
            sx = fmaf(v.x, v.x, fmaf(v.y, v.y, fmaf(v.z, v.z, fmaf(v.w, v.w, sx))));
            xu[2 * q]     = pack_bf16(v.x, v.y);
            xu[2 * q + 1] = pack_bf16(v.z, v.w);
            const float4 u = *(const float4*)(yr + 4 * q);
            sy = fmaf(u.x, u.x, fmaf(u.y, u.y, fmaf(u.z, u.z, fmaf(u.w, u.w, sy))));
            yu[2 * q]     = pack_bf16(u.x, u.y);
            yu[2 * q + 1] = pack_bf16(u.z, u.w);
        }
#pragma unroll
        for (int q = 0; q < 4; ++q) {
            *(uint4*)(&xbf[r][h * 32 + q * 8]) = make_uint4(xu[4*q], xu[4*q+1], xu[4*q+2], xu[4*q+3]);
            *(uint4*)(&ybf[r][h * 32 + q * 8]) = make_uint4(yu[4*q], yu[4*q+1], yu[4*q+2], yu[4*q+3]);
        }
        xpart[r][h] = sx; ypart[r][h] = sy;
    }
    __syncthreads();
    if (t < 128) x2s[t] = xpart[t][0] + xpart[t][1];
    else         y2s[t - 128] = ypart[t - 128][0] + ypart[t - 128][1];
    __syncthreads();

    const int w    = t >> 6, lane = t & 63;
    const int wr   = (w >> 1) << 6, wc = (w & 1) << 6;   // wave's 64x64 quadrant
    const int fr   = lane & 15;
    const int fk   = (lane >> 4) << 3;                   // k-subgroup base

    f32x4 acc[4][4] = {};
#pragma unroll
    for (int c = 0; c < 2; ++c) {
        short8 A[4], Bf[4];
#pragma unroll
        for (int a = 0; a < 4; ++a)
            A[a] = *(const short8*)(&xbf[wr + (a << 4) + fr][(c << 5) + fk]);
#pragma unroll
        for (int bb = 0; bb < 4; ++bb)
            Bf[bb] = *(const short8*)(&ybf[wc + (bb << 4) + fr][(c << 5) + fk]);
#pragma unroll
        for (int a = 0; a < 4; ++a)
#pragma unroll
            for (int bb = 0; bb < 4; ++bb)
                acc[a][bb] = __builtin_amdgcn_mfma_f32_16x16x32_bf16(
                    A[a], Bf[bb], acc[a][bb], 0, 0, 0);
    }
    __syncthreads();   // frag reads done -> alias xbf/ybf as dt

    {   // epilogue: C/D map col=lane&15, row=(lane>>4)*4+reg (m89-verified)
        const int er = (lane >> 4) << 2;
        const int ec = lane & 15;
#pragma unroll
        for (int a = 0; a < 4; ++a) {
#pragma unroll
            for (int bb = 0; bb < 4; ++bb) {
                const int lcol = wc + (bb << 4) + ec;
                const float yy = y2s[lcol];
#pragma unroll
                for (int reg = 0; reg < 4; ++reg) {
                    const int lrow = wr + (a << 4) + er + reg;
                    const float d = (x2s[lrow] + yy - 2.f * acc[a][bb][reg]) * LOG2E_F;
                    __hip_bfloat16 hh = __float2bfloat16(d);
                    dt[lrow][lcol] = *(unsigned short*)&hh;
                }
            }
        }
    }
    __syncthreads();

    {   // write-out: row r -> D[gi][gi+tj .. +127]: contiguous 128 shorts.
        unsigned short* Dg = Dws + (size_t)b * PBATCH;
#pragma unroll 4
        for (int r = w; r < 128; r += 4) {
            const int gi = ti + r;
            const int base = 512 * gi + (gi + tj);
            Dg[base + lane]      = dt[r][lane];
            Dg[base + lane + 64] = dt[r][lane + 64];
        }
    }
}

// ---------------- Phase 2: band-pipelined DP (round-12 version, 138 us).
// 512 threads (8 waves = 2/SIMD), thread tid owns row tid; wave wv does band k
// at epoch e = wv+k; one raw barrier per epoch (71); 2 uint4 band loads with
// sched_barrier-pinned prefetch; all-register steps.
__global__ __launch_bounds__(512, 1) void sdtw_dp(const unsigned short* __restrict__ Dws,
                                                  float* __restrict__ out) {
    __shared__ __align__(16) float hnd[3][8][16];
    const int b    = blockIdx.x;
    const int tid  = threadIdx.x;        // row
    const int lane = tid & 63;
    const int wv   = tid >> 6;

    if (tid < 384) ((float*)hnd)[tid] = LARGE_F;
    __syncthreads();

    const char* Dbase = (const char*)Dws;
    unsigned off = (unsigned)b * 525312u + (unsigned)tid * 1024u;  // row tid, band 0

    float cur = LARGE_F;                     // R_{p-1}[tid]
    float nw  = (tid == 0) ? 0.f : LARGE_F;  // R_{p-2}[tid-1]; corner (0,0)=0
    float res = 0.f;
    float hband_prev = LARGE_F;
    const bool haveup = (wv > 0);
    const bool l0     = (lane == 0);

    uint4 c0 = *(const uint4*)(Dbase + off);
    uint4 c1 = *(const uint4*)(Dbase + off + 16);
    off += 32;

    int m0 = 0, m1 = 2;                      // e%3, (e-1)%3
#pragma unroll 1
    for (int e = 0; e < 71; ++e) {
        const int k = e - wv;
        if (0 <= k && k < 64) {
            const unsigned q[8] = {c0.x, c0.y, c0.z, c0.w, c1.x, c1.y, c1.z, c1.w};
            float d[16];
#pragma unroll
            for (int u = 0; u < 16; ++u) {
                const unsigned w_ = q[u >> 1];
                d[u] = __uint_as_float((u & 1) ? (w_ & 0xffff0000u) : (w_ << 16));
            }
            c0 = *(const uint4*)(Dbase + off);       // k=63 overshoots into slop
            c1 = *(const uint4*)(Dbase + off + 16);
            off += 32;
            __builtin_amdgcn_sched_barrier(0);       // pin loads before compute

            const float hband = haveup ? hnd[m1][wv - 1][lane & 15] : LARGE_F;
            float h[16];
#pragma unroll
            for (int u = 0; u < 16; ++u) {
                const float nvec = wave_shr1(cur, LARGE_F);
                const float hu = __int_as_float(__builtin_amdgcn_readlane(
                    __float_as_int((u == 0) ? hband_prev : hband),
                    (u == 0) ? 15 : (u - 1)));
                const float n  = (haveup && l0) ? hu : nvec;
                const float mn = fminf(fminf(cur, n), nw);
                const float mx = fmaxf(fmaxf(cur, n), nw);
                const float md = __builtin_amdgcn_fmed3f(cur, n, nw);
                const float sm = mn - log2f(1.f + exp2f(mn - md) + exp2f(mn - mx));
                const float newc = d[u] + sm;
                h[u] = newc;
                if (u == 14) { if (k == 63) res = newc; }     // cell (511,511)
                nw = n; cur = newc;
            }
            hband_prev = hband;
            if (lane == 63) {
                *(float4*)(&hnd[m0][wv][0])  = make_float4(h[0], h[1], h[2], h[3]);
                *(float4*)(&hnd[m0][wv][4])  = make_float4(h[4], h[5], h[6], h[7]);
                *(float4*)(&hnd[m0][wv][8])  = make_float4(h[8], h[9], h[10], h[11]);
                *(float4*)(&hnd[m0][wv][12]) = make_float4(h[12], h[13], h[14], h[15]);
            }
        }
        asm volatile("s_waitcnt lgkmcnt(0)" ::: "memory");
        __builtin_amdgcn_s_barrier();        // raw: vmcnt NOT drained
        m0 = (m0 == 2) ? 0 : m0 + 1;
        m1 = (m1 == 2) ? 0 : m1 + 1;
    }
    if (tid == 511) out[b] = res * LN2_F;
}

// ---------------- Fallback (only if ws too small): fused, correct, slow.
__global__ __launch_bounds__(512) void sdtw_fused_naive(const float* __restrict__ x,
                                                        const float* __restrict__ y,
                                                        float* __restrict__ out) {
    __shared__ float rbuf[3][NN];
    __shared__ float y2s[MM];
    const int b = blockIdx.x;
    const int i = threadIdx.x;

    const float* xrow  = x + ((size_t)b * NN + i) * KK;
    const float* ybase = y + (size_t)b * MM * KK;

    float xr[KK];
    float x2 = 0.f;
#pragma unroll
    for (int k = 0; k < KK; k += 4) {
        const float4 v = *(const float4*)(xrow + k);
        xr[k] = v.x; xr[k + 1] = v.y; xr[k + 2] = v.z; xr[k + 3] = v.w;
        x2 = fmaf(v.x, v.x, fmaf(v.y, v.y, fmaf(v.z, v.z, fmaf(v.w, v.w, x2))));
    }
    {
        const float* yrow = ybase + (size_t)i * KK;
        float s = 0.f;
#pragma unroll
        for (int k = 0; k < KK; k += 4) {
            const float4 v = *(const float4*)(yrow + k);
            s = fmaf(v.x, v.x, s); s = fmaf(v.y, v.y, s);
            s = fmaf(v.z, v.z, s); s = fmaf(v.w, v.w, s);
        }
        y2s[i] = s;
    }
    rbuf[0][i] = LARGE_F;
    rbuf[1][i] = LARGE_F;
    rbuf[2][i] = LARGE_F;

    float* row_w  = rbuf[0];
    float* row_p  = rbuf[2];
    float* row_p2 = rbuf[1];
    __syncthreads();

    float cur = LARGE_F;
    for (int p = 0; p < NN + MM - 1; ++p) {
        const int j0 = p - i;
        const bool valid = (j0 >= 0) && (j0 < MM);
        float dg = 0.f;
        if (valid) {
            const float* yrow = ybase + (size_t)j0 * KK;
            float dot = 0.f;
#pragma unroll
            for (int k = 0; k < KK; k += 4) {
                const float4 v = *(const float4*)(yrow + k);
                dot = fmaf(xr[k], v.x, dot);
                dot = fmaf(xr[k + 1], v.y, dot);
                dot = fmaf(xr[k + 2], v.z, dot);
                dot = fmaf(xr[k + 3], v.w, dot);
            }
            dg = x2 + y2s[j0] - 2.f * dot;
        }
        const float r_w  = row_p[i];
        const float r_n  = (i > 0) ? row_p[i - 1] : LARGE_F;
        const float r_nw = (i > 0) ? row_p2[i - 1] : ((p == 0) ? 0.f : LARGE_F);

        const float m = fminf(fminf(r_nw, r_n), r_w);
        const float s = __expf(m - r_nw) + __expf(m - r_n) + __expf(m - r_w);
        const float softmin = m - __logf(s);

        cur = valid ? (dg + softmin) : LARGE_F;
        row_w[i] = cur;
        __syncthreads();

        float* tmp = row_w;
        row_w = row_p2; row_p2 = row_p; row_p = tmp;
    }
    if (i == NN - 1) out[b] = cur;
}

extern "C" void kernel_launch(void* const* d_in, const int* in_sizes, int n_in,
                              void* d_out, int out_size, void* d_ws, size_t ws_size,
                              hipStream_t stream) {
    const float* x = (const float*)d_in[0];
    const float* y = (const float*)d_in[1];
    float* out = (float*)d_out;

    if (ws_size >= NEED) {   // 67,244,032 B
        unsigned short* Dws = (unsigned short*)d_ws;
        sdtw_dist<<<dim3(2048), 256, 0, stream>>>(x, y, Dws);
        sdtw_dp<<<dim3(BB), 512, 0, stream>>>(Dws, out);
    } else {
        sdtw_fused_naive<<<dim3(BB), 512, 0, stream>>>(x, y, out);
    }
}

// Round 15
// 123.737 us; speedup vs baseline: 1.6622x; 1.3318x over previous
//
#include <hip/hip_runtime.h>
#include <hip/hip_bf16.h>

#define LARGE_F 1e30f
#define LOG2E_F 1.4426950408889634f
#define LN2_F   0.6931471805599453f

constexpr int BB = 128;
constexpr int NN = 512;
constexpr int MM = 512;
constexpr int KK = 64;
// D layout: bf16, short index = 512*i + p (p = i+j). Row i spans [513i, 513i+511].
constexpr int PBATCH = 262656;              // shorts per batch (525,312 B)
constexpr size_t NEED = (size_t)BB * PBATCH * 2 + 4096;  // + band-64 overshoot slop

typedef __attribute__((ext_vector_type(8))) short short8;   // 8 bf16 (guide §3)
typedef __attribute__((ext_vector_type(4))) float f32x4;

// lane i <- lane i-1 via DPP wave_shr:1 (VALU). Lane 0 receives `bound`.
__device__ __forceinline__ float wave_shr1(float v, float bound) {
    const int r = __builtin_amdgcn_update_dpp(__float_as_int(bound), __float_as_int(v),
                                              0x138, 0xf, 0xf, false);
    return __int_as_float(r);
}

__device__ __forceinline__ unsigned pack_bf16(float a, float b) {
    __hip_bfloat16 ha = __float2bfloat16(a);
    __hip_bfloat16 hb = __float2bfloat16(b);
    return (unsigned)*(unsigned short*)&ha | ((unsigned)*(unsigned short*)&hb << 16);
}

// Raw-instruction transcendentals (v_exp_f32 / v_log_f32, ~1 ulp). The libm
// exp2f/log2f fallbacks are multi-instruction __ocml calls -- 3 of them per DP
// cell were ~2.3x the cell's entire VALU budget (round-14 postmortem).
__device__ __forceinline__ float fast_exp2(float x) { return __builtin_amdgcn_exp2f(x); }
__device__ __forceinline__ float fast_log2(float x) { return __builtin_amdgcn_logf(x); }

// ---------------- Phase 1 (MFMA): D[i][p] = ||x_i - y_j||^2 * log2e (bf16).
// G = X·Y^T via mfma_f32_16x16x32_bf16; x2/y2 from original f32. 128x128 tile,
// 4 waves (each a 64x64 quadrant). XCD swizzle: batch b's 16 tiles -> XCD b%8.
__global__ __launch_bounds__(256, 2) void sdtw_dist(const float* __restrict__ x,
                                                    const float* __restrict__ y,
                                                    unsigned short* __restrict__ Dws) {
    __shared__ __align__(16) unsigned short xbf[128][88];   // stride 88: 2-way banks
    __shared__ __align__(16) unsigned short ybf[128][88];
    __shared__ float x2s[128], y2s[128];
    __shared__ float xpart[128][2], ypart[128][2];
    unsigned short (*dt)[132] = (unsigned short (*)[132])(&xbf[0][0]);  // 33792B

    const int bid  = blockIdx.x;               // 0..2047
    const int xcd  = bid & 7, sidx = bid >> 3;
    const int g    = sidx >> 4, tile = sidx & 15;
    const int b    = xcd + (g << 3);           // batch: tiles of b all on XCD b%8
    const int ti   = (tile >> 2) << 7, tj = (tile & 3) << 7;
    const int t    = threadIdx.x;

    const float* xb = x + ((size_t)b * NN + ti) * KK;
    const float* yb = y + ((size_t)b * MM + tj) * KK;

    {   // stage f32 -> bf16 LDS + f32 partial squared norms
        const int r = t >> 1, h = t & 1;
        const float* xr = xb + r * KK + h * 32;
        const float* yr = yb + r * KK + h * 32;
        float sx = 0.f, sy = 0.f;
        unsigned xu[16], yu[16];
#pragma unroll
        for (int q = 0; q < 8; ++q) {
            const float4 v = *(const float4*)(xr + 4 * q);
            sx = fmaf(v.x, v.x, fmaf(v.y, v.y, fmaf(v.z, v.z, fmaf(v.w, v.w, sx))));
            xu[2 * q]     = pack_bf16(v.x, v.y);
            xu[2 * q + 1] = pack_bf16(v.z, v.w);
            const float4 u = *(const float4*)(yr + 4 * q);
            sy = fmaf(u.x, u.x, fmaf(u.y, u.y, fmaf(u.z, u.z, fmaf(u.w, u.w, sy))));
            yu[2 * q]     = pack_bf16(u.x, u.y);
            yu[2 * q + 1] = pack_bf16(u.z, u.w);
        }
#pragma unroll
        for (int q = 0; q < 4; ++q) {
            *(uint4*)(&xbf[r][h * 32 + q * 8]) = make_uint4(xu[4*q], xu[4*q+1], xu[4*q+2], xu[4*q+3]);
            *(uint4*)(&ybf[r][h * 32 + q * 8]) = make_uint4(yu[4*q], yu[4*q+1], yu[4*q+2], yu[4*q+3]);
        }
        xpart[r][h] = sx; ypart[r][h] = sy;
    }
    __syncthreads();
    if (t < 128) x2s[t] = xpart[t][0] + xpart[t][1];
    else         y2s[t - 128] = ypart[t - 128][0] + ypart[t - 128][1];
    __syncthreads();

    const int w    = t >> 6, lane = t & 63;
    const int wr   = (w >> 1) << 6, wc = (w & 1) << 6;   // wave's 64x64 quadrant
    const int fr   = lane & 15;
    const int fk   = (lane >> 4) << 3;                   // k-subgroup base

    f32x4 acc[4][4] = {};
#pragma unroll
    for (int c = 0; c < 2; ++c) {
        short8 A[4], Bf[4];
#pragma unroll
        for (int a = 0; a < 4; ++a)
            A[a] = *(const short8*)(&xbf[wr + (a << 4) + fr][(c << 5) + fk]);
#pragma unroll
        for (int bb = 0; bb < 4; ++bb)
            Bf[bb] = *(const short8*)(&ybf[wc + (bb << 4) + fr][(c << 5) + fk]);
#pragma unroll
        for (int a = 0; a < 4; ++a)
#pragma unroll
            for (int bb = 0; bb < 4; ++bb)
                acc[a][bb] = __builtin_amdgcn_mfma_f32_16x16x32_bf16(
                    A[a], Bf[bb], acc[a][bb], 0, 0, 0);
    }
    __syncthreads();   // frag reads done -> alias xbf/ybf as dt

    {   // epilogue: C/D map col=lane&15, row=(lane>>4)*4+reg (m89-verified)
        const int er = (lane >> 4) << 2;
        const int ec = lane & 15;
#pragma unroll
        for (int a = 0; a < 4; ++a) {
#pragma unroll
            for (int bb = 0; bb < 4; ++bb) {
                const int lcol = wc + (bb << 4) + ec;
                const float yy = y2s[lcol];
#pragma unroll
                for (int reg = 0; reg < 4; ++reg) {
                    const int lrow = wr + (a << 4) + er + reg;
                    const float d = (x2s[lrow] + yy - 2.f * acc[a][bb][reg]) * LOG2E_F;
                    __hip_bfloat16 hh = __float2bfloat16(d);
                    dt[lrow][lcol] = *(unsigned short*)&hh;
                }
            }
        }
    }
    __syncthreads();

    {   // write-out: row r -> D[gi][gi+tj .. +127]: contiguous 128 shorts.
        unsigned short* Dg = Dws + (size_t)b * PBATCH;
#pragma unroll 4
        for (int r = w; r < 128; r += 4) {
            const int gi = ti + r;
            const int base = 512 * gi + (gi + tj);
            Dg[base + lane]      = dt[r][lane];
            Dg[base + lane + 64] = dt[r][lane + 64];
        }
    }
}

// ---------------- Phase 2: band-pipelined DP (round-12/14 structure; only the
// transcendentals changed to raw v_exp_f32/v_log_f32 builtins).
__global__ __launch_bounds__(512, 1) void sdtw_dp(const unsigned short* __restrict__ Dws,
                                                  float* __restrict__ out) {
    __shared__ __align__(16) float hnd[3][8][16];
    const int b    = blockIdx.x;
    const int tid  = threadIdx.x;        // row
    const int lane = tid & 63;
    const int wv   = tid >> 6;

    if (tid < 384) ((float*)hnd)[tid] = LARGE_F;
    __syncthreads();

    const char* Dbase = (const char*)Dws;
    unsigned off = (unsigned)b * 525312u + (unsigned)tid * 1024u;  // row tid, band 0

    float cur = LARGE_F;                     // R_{p-1}[tid]
    float nw  = (tid == 0) ? 0.f : LARGE_F;  // R_{p-2}[tid-1]; corner (0,0)=0
    float res = 0.f;
    float hband_prev = LARGE_F;
    const bool haveup = (wv > 0);
    const bool l0     = (lane == 0);

    uint4 c0 = *(const uint4*)(Dbase + off);
    uint4 c1 = *(const uint4*)(Dbase + off + 16);
    off += 32;

    int m0 = 0, m1 = 2;                      // e%3, (e-1)%3
#pragma unroll 1
    for (int e = 0; e < 71; ++e) {
        const int k = e - wv;
        if (0 <= k && k < 64) {
            const unsigned q[8] = {c0.x, c0.y, c0.z, c0.w, c1.x, c1.y, c1.z, c1.w};
            float d[16];
#pragma unroll
            for (int u = 0; u < 16; ++u) {
                const unsigned w_ = q[u >> 1];
                d[u] = __uint_as_float((u & 1) ? (w_ & 0xffff0000u) : (w_ << 16));
            }
            c0 = *(const uint4*)(Dbase + off);       // k=63 overshoots into slop
            c1 = *(const uint4*)(Dbase + off + 16);
            off += 32;
            __builtin_amdgcn_sched_barrier(0);       // pin loads before compute

            const float hband = haveup ? hnd[m1][wv - 1][lane & 15] : LARGE_F;
            float h[16];
#pragma unroll
            for (int u = 0; u < 16; ++u) {
                const float nvec = wave_shr1(cur, LARGE_F);
                const float hu = __int_as_float(__builtin_amdgcn_readlane(
                    __float_as_int((u == 0) ? hband_prev : hband),
                    (u == 0) ? 15 : (u - 1)));
                const float n  = (haveup && l0) ? hu : nvec;
                const float mn = fminf(fminf(cur, n), nw);
                const float mx = fmaxf(fmaxf(cur, n), nw);
                const float md = __builtin_amdgcn_fmed3f(cur, n, nw);
                const float sm = mn - fast_log2(1.f + fast_exp2(mn - md) + fast_exp2(mn - mx));
                const float newc = d[u] + sm;
                h[u] = newc;
                if (u == 14) { if (k == 63) res = newc; }     // cell (511,511)
                nw = n; cur = newc;
            }
            hband_prev = hband;
            if (lane == 63) {
                *(float4*)(&hnd[m0][wv][0])  = make_float4(h[0], h[1], h[2], h[3]);
                *(float4*)(&hnd[m0][wv][4])  = make_float4(h[4], h[5], h[6], h[7]);
                *(float4*)(&hnd[m0][wv][8])  = make_float4(h[8], h[9], h[10], h[11]);
                *(float4*)(&hnd[m0][wv][12]) = make_float4(h[12], h[13], h[14], h[15]);
            }
        }
        asm volatile("s_waitcnt lgkmcnt(0)" ::: "memory");
        __builtin_amdgcn_s_barrier();        // raw: vmcnt NOT drained
        m0 = (m0 == 2) ? 0 : m0 + 1;
        m1 = (m1 == 2) ? 0 : m1 + 1;
    }
    if (tid == 511) out[b] = res * LN2_F;
}

// ---------------- Fallback (only if ws too small): fused, correct, slow.
__global__ __launch_bounds__(512) void sdtw_fused_naive(const float* __restrict__ x,
                                                        const float* __restrict__ y,
                                                        float* __restrict__ out) {
    __shared__ float rbuf[3][NN];
    __shared__ float y2s[MM];
    const int b = blockIdx.x;
    const int i = threadIdx.x;

    const float* xrow  = x + ((size_t)b * NN + i) * KK;
    const float* ybase = y + (size_t)b * MM * KK;

    float xr[KK];
    float x2 = 0.f;
#pragma unroll
    for (int k = 0; k < KK; k += 4) {
        const float4 v = *(const float4*)(xrow + k);
        xr[k] = v.x; xr[k + 1] = v.y; xr[k + 2] = v.z; xr[k + 3] = v.w;
        x2 = fmaf(v.x, v.x, fmaf(v.y, v.y, fmaf(v.z, v.z, fmaf(v.w, v.w, x2))));
    }
    {
        const float* yrow = ybase + (size_t)i * KK;
        float s = 0.f;
#pragma unroll
        for (int k = 0; k < KK; k += 4) {
            const float4 v = *(const float4*)(yrow + k);
            s = fmaf(v.x, v.x, s); s = fmaf(v.y, v.y, s);
            s = fmaf(v.z, v.z, s); s = fmaf(v.w, v.w, s);
        }
        y2s[i] = s;
    }
    rbuf[0][i] = LARGE_F;
    rbuf[1][i] = LARGE_F;
    rbuf[2][i] = LARGE_F;

    float* row_w  = rbuf[0];
    float* row_p  = rbuf[2];
    float* row_p2 = rbuf[1];
    __syncthreads();

    float cur = LARGE_F;
    for (int p = 0; p < NN + MM - 1; ++p) {
        const int j0 = p - i;
        const bool valid = (j0 >= 0) && (j0 < MM);
        float dg = 0.f;
        if (valid) {
            const float* yrow = ybase + (size_t)j0 * KK;
            float dot = 0.f;
#pragma unroll
            for (int k = 0; k < KK; k += 4) {
                const float4 v = *(const float4*)(yrow + k);
                dot = fmaf(xr[k], v.x, dot);
                dot = fmaf(xr[k + 1], v.y, dot);
                dot = fmaf(xr[k + 2], v.z, dot);
                dot = fmaf(xr[k + 3], v.w, dot);
            }
            dg = x2 + y2s[j0] - 2.f * dot;
        }
        const float r_w  = row_p[i];
        const float r_n  = (i > 0) ? row_p[i - 1] : LARGE_F;
        const float r_nw = (i > 0) ? row_p2[i - 1] : ((p == 0) ? 0.f : LARGE_F);

        const float m = fminf(fminf(r_nw, r_n), r_w);
        const float s = __expf(m - r_nw) + __expf(m - r_n) + __expf(m - r_w);
        const float softmin = m - __logf(s);

        cur = valid ? (dg + softmin) : LARGE_F;
        row_w[i] = cur;
        __syncthreads();

        float* tmp = row_w;
        row_w = row_p2; row_p2 = row_p; row_p = tmp;
    }
    if (i == NN - 1) out[b] = cur;
}

extern "C" void kernel_launch(void* const* d_in, const int* in_sizes, int n_in,
                              void* d_out, int out_size, void* d_ws, size_t ws_size,
                              hipStream_t stream) {
    const float* x = (const float*)d_in[0];
    const float* y = (const float*)d_in[1];
    float* out = (float*)d_out;

    if (ws_size >= NEED) {   // 67,244,032 B
        unsigned short* Dws = (unsigned short*)d_ws;
        sdtw_dist<<<dim3(2048), 256, 0, stream>>>(x, y, Dws);
        sdtw_dp<<<dim3(BB), 512, 0, stream>>>(Dws, out);
    } else {
        sdtw_fused_naive<<<dim3(BB), 512, 0, stream>>>(x, y, out);
    }
}

// Round 16
// 107.482 us; speedup vs baseline: 1.9136x; 1.1512x over previous
//
#include <hip/hip_runtime.h>
#include <hip/hip_bf16.h>

#define LARGE_F 1e30f
#define LOG2E_F 1.4426950408889634f
#define LN2_F   0.6931471805599453f

constexpr int BB = 128;
constexpr int NN = 512;
constexpr int MM = 512;
constexpr int KK = 64;
// D layout: bf16, short index = 512*i + p (p = i+j). Row i spans [513i, 513i+511].
constexpr int PBATCH = 262656;              // shorts per batch (525,312 B)
constexpr size_t NEED = (size_t)BB * PBATCH * 2 + 4096;  // + band-64 overshoot slop

typedef __attribute__((ext_vector_type(8))) short short8;   // 8 bf16 (guide §3)
typedef __attribute__((ext_vector_type(4))) float f32x4;

// lane i <- lane i-1 via DPP wave_shr:1 (VALU). Lane 0 receives `bound`.
__device__ __forceinline__ float wave_shr1(float v, float bound) {
    const int r = __builtin_amdgcn_update_dpp(__float_as_int(bound), __float_as_int(v),
                                              0x138, 0xf, 0xf, false);
    return __int_as_float(r);
}

__device__ __forceinline__ unsigned pack_bf16(float a, float b) {
    __hip_bfloat16 ha = __float2bfloat16(a);
    __hip_bfloat16 hb = __float2bfloat16(b);
    return (unsigned)*(unsigned short*)&ha | ((unsigned)*(unsigned short*)&hb << 16);
}

// Raw-instruction transcendentals (v_exp_f32 / v_log_f32, ~1 ulp) -- the libm
// exp2f/log2f __ocml calls were 2.3x the DP cell's VALU budget (round 14->15).
__device__ __forceinline__ float fast_exp2(float x) { return __builtin_amdgcn_exp2f(x); }
__device__ __forceinline__ float fast_log2(float x) { return __builtin_amdgcn_logf(x); }

// ---------------- Phase 1 (MFMA): D[i][p] = ||x_i - y_j||^2 * log2e (bf16).
// G = X·Y^T via mfma_f32_16x16x32_bf16; x2/y2 from original f32. 128x128 tile,
// 4 waves (each a 64x64 quadrant). XCD swizzle: batch b's 16 tiles -> XCD b%8.
__global__ __launch_bounds__(256, 2) void sdtw_dist(const float* __restrict__ x,
                                                    const float* __restrict__ y,
                                                    unsigned short* __restrict__ Dws) {
    __shared__ __align__(16) unsigned short xbf[128][88];   // stride 88: 2-way banks
    __shared__ __align__(16) unsigned short ybf[128][88];
    __shared__ float x2s[128], y2s[128];
    __shared__ float xpart[128][2], ypart[128][2];
    unsigned short (*dt)[132] = (unsigned short (*)[132])(&xbf[0][0]);  // 33792B

    const int bid  = blockIdx.x;               // 0..2047
    const int xcd  = bid & 7, sidx = bid >> 3;
    const int g    = sidx >> 4, tile = sidx & 15;
    const int b    = xcd + (g << 3);           // batch: tiles of b all on XCD b%8
    const int ti   = (tile >> 2) << 7, tj = (tile & 3) << 7;
    const int t    = threadIdx.x;

    const float* xb = x + ((size_t)b * NN + ti) * KK;
    const float* yb = y + ((size_t)b * MM + tj) * KK;

    {   // stage f32 -> bf16 LDS + f32 partial squared norms
        const int r = t >> 1, h = t & 1;
        const float* xr = xb + r * KK + h * 32;
        const float* yr = yb + r * KK + h * 32;
        float sx = 0.f, sy = 0.f;
        unsigned xu[16], yu[16];
#pragma unroll
        for (int q = 0; q < 8; ++q) {
            const float4 v = *(const float4*)(xr + 4 * q);
            sx = fmaf(v.x, v.x, fmaf(v.y, v.y, fmaf(v.z, v.z, fmaf(v.w, v.w, sx))));
            xu[2 * q]     = pack_bf16(v.x, v.y);
            xu[2 * q + 1] = pack_bf16(v.z, v.w);
            const float4 u = *(const float4*)(yr + 4 * q);
            sy = fmaf(u.x, u.x, fmaf(u.y, u.y, fmaf(u.z, u.z, fmaf(u.w, u.w, sy))));
            yu[2 * q]     = pack_bf16(u.x, u.y);
            yu[2 * q + 1] = pack_bf16(u.z, u.w);
        }
#pragma unroll
        for (int q = 0; q < 4; ++q) {
            *(uint4*)(&xbf[r][h * 32 + q * 8]) = make_uint4(xu[4*q], xu[4*q+1], xu[4*q+2], xu[4*q+3]);
            *(uint4*)(&ybf[r][h * 32 + q * 8]) = make_uint4(yu[4*q], yu[4*q+1], yu[4*q+2], yu[4*q+3]);
        }
        xpart[r][h] = sx; ypart[r][h] = sy;
    }
    __syncthreads();
    if (t < 128) x2s[t] = xpart[t][0] + xpart[t][1];
    else         y2s[t - 128] = ypart[t - 128][0] + ypart[t - 128][1];
    __syncthreads();

    const int w    = t >> 6, lane = t & 63;
    const int wr   = (w >> 1) << 6, wc = (w & 1) << 6;   // wave's 64x64 quadrant
    const int fr   = lane & 15;
    const int fk   = (lane >> 4) << 3;                   // k-subgroup base

    f32x4 acc[4][4] = {};
#pragma unroll
    for (int c = 0; c < 2; ++c) {
        short8 A[4], Bf[4];
#pragma unroll
        for (int a = 0; a < 4; ++a)
            A[a] = *(const short8*)(&xbf[wr + (a << 4) + fr][(c << 5) + fk]);
#pragma unroll
        for (int bb = 0; bb < 4; ++bb)
            Bf[bb] = *(const short8*)(&ybf[wc + (bb << 4) + fr][(c << 5) + fk]);
#pragma unroll
        for (int a = 0; a < 4; ++a)
#pragma unroll
            for (int bb = 0; bb < 4; ++bb)
                acc[a][bb] = __builtin_amdgcn_mfma_f32_16x16x32_bf16(
                    A[a], Bf[bb], acc[a][bb], 0, 0, 0);
    }
    __syncthreads();   // frag reads done -> alias xbf/ybf as dt

    {   // epilogue: C/D map col=lane&15, row=(lane>>4)*4+reg (m89-verified)
        const int er = (lane >> 4) << 2;
        const int ec = lane & 15;
#pragma unroll
        for (int a = 0; a < 4; ++a) {
#pragma unroll
            for (int bb = 0; bb < 4; ++bb) {
                const int lcol = wc + (bb << 4) + ec;
                const float yy = y2s[lcol];
#pragma unroll
                for (int reg = 0; reg < 4; ++reg) {
                    const int lrow = wr + (a << 4) + er + reg;
                    const float d = (x2s[lrow] + yy - 2.f * acc[a][bb][reg]) * LOG2E_F;
                    __hip_bfloat16 hh = __float2bfloat16(d);
                    dt[lrow][lcol] = *(unsigned short*)&hh;
                }
            }
        }
    }
    __syncthreads();

    {   // write-out: row r -> D[gi][gi+tj .. +127]: contiguous 128 shorts.
        unsigned short* Dg = Dws + (size_t)b * PBATCH;
#pragma unroll 4
        for (int r = w; r < 128; r += 4) {
            const int gi = ti + r;
            const int base = 512 * gi + (gi + tj);
            Dg[base + lane]      = dt[r][lane];
            Dg[base + lane + 64] = dt[r][lane + 64];
        }
    }
}

// ---------------- Phase 2: WINDOWED band-pipelined DP. Thread tid owns row
// tid; wave wv processes only bands k in [4wv, 4wv+35] (the other 28 bands
// contain zero valid cells for its rows -- p < i or p > i+511). Epoch e=k+wv,
// 71 epochs, one raw barrier each. Boundary handoff via mod-3 LDS buffers;
// window-entry hband_prev comes from the (e-2)%3 buffer (verified race-free).
// Consumers only need producer bands within the producer's window; stale LDS
// beyond it feeds provably-invalid (j>=512) cells only.
__global__ __launch_bounds__(512, 1) void sdtw_dp(const unsigned short* __restrict__ Dws,
                                                  float* __restrict__ out) {
    __shared__ __align__(16) float hnd[3][8][16];
    const int b    = blockIdx.x;
    const int tid  = threadIdx.x;        // row
    const int lane = tid & 63;
    const int wv   = tid >> 6;
    const int k0   = wv << 2;            // window start band

    if (tid < 384) ((float*)hnd)[tid] = LARGE_F;
    __syncthreads();

    const char* Dbase = (const char*)Dws;
    // Start at band k0 (byte offset 32 per band).
    unsigned off = (unsigned)b * 525312u + (unsigned)tid * 1024u + (unsigned)(k0 << 5);

    float cur = LARGE_F;                     // R_{p-1}[tid]
    float nw  = (tid == 0) ? 0.f : LARGE_F;  // R_{p-2}[tid-1]; corner (0,0)=0
    float res = 0.f;
    float hband_prev = LARGE_F;
    const bool haveup = (wv > 0);
    const bool l0     = (lane == 0);

    uint4 c0 = *(const uint4*)(Dbase + off);
    uint4 c1 = *(const uint4*)(Dbase + off + 16);
    off += 32;

    int m0 = 0, m1 = 2;                      // e%3, (e-1)%3
#pragma unroll 1
    for (int e = 0; e < 71; ++e) {
        const int k = e - wv;
        if (k >= k0 && k < k0 + 36) {
            const unsigned q[8] = {c0.x, c0.y, c0.z, c0.w, c1.x, c1.y, c1.z, c1.w};
            float d[16];
#pragma unroll
            for (int u = 0; u < 16; ++u) {
                const unsigned w_ = q[u >> 1];
                d[u] = __uint_as_float((u & 1) ? (w_ & 0xffff0000u) : (w_ << 16));
            }
            c0 = *(const uint4*)(Dbase + off);       // last band overshoots: slop
            c1 = *(const uint4*)(Dbase + off + 16);
            off += 32;
            __builtin_amdgcn_sched_barrier(0);       // pin loads before compute

            // Window entry: hband_prev = boundary at diag 16*k0-1, written by
            // wave wv-1 two epochs ago -> (e-2)%3 buffer, still live.
            if (k == k0 && haveup) {
                const int m2 = 3 - m0 - m1;
                hband_prev = hnd[m2][wv - 1][15];
            }
            const float hband = haveup ? hnd[m1][wv - 1][lane & 15] : LARGE_F;
            float h[16];
#pragma unroll
            for (int u = 0; u < 16; ++u) {
                const float nvec = wave_shr1(cur, LARGE_F);
                const float hu = __int_as_float(__builtin_amdgcn_readlane(
                    __float_as_int((u == 0) ? hband_prev : hband),
                    (u == 0) ? 15 : (u - 1)));
                const float n  = (haveup && l0) ? hu : nvec;
                const float mn = fminf(fminf(cur, n), nw);
                const float mx = fmaxf(fmaxf(cur, n), nw);
                const float md = __builtin_amdgcn_fmed3f(cur, n, nw);
                const float sm = mn - fast_log2(1.f + fast_exp2(mn - md) + fast_exp2(mn - mx));
                const float newc = d[u] + sm;
                h[u] = newc;
                nw = n; cur = newc;
            }
            if (k == 63) res = h[14];                // cell (511,511) at tid 511
            hband_prev = hband;
            if (lane == 63) {
                *(float4*)(&hnd[m0][wv][0])  = make_float4(h[0], h[1], h[2], h[3]);
                *(float4*)(&hnd[m0][wv][4])  = make_float4(h[4], h[5], h[6], h[7]);
                *(float4*)(&hnd[m0][wv][8])  = make_float4(h[8], h[9], h[10], h[11]);
                *(float4*)(&hnd[m0][wv][12]) = make_float4(h[12], h[13], h[14], h[15]);
            }
        }
        asm volatile("s_waitcnt lgkmcnt(0)" ::: "memory");
        __builtin_amdgcn_s_barrier();        // raw: vmcnt NOT drained
        m0 = (m0 == 2) ? 0 : m0 + 1;
        m1 = (m1 == 2) ? 0 : m1 + 1;
    }
    if (tid == 511) out[b] = res * LN2_F;
}

// ---------------- Fallback (only if ws too small): fused, correct, slow.
__global__ __launch_bounds__(512) void sdtw_fused_naive(const float* __restrict__ x,
                                                        const float* __restrict__ y,
                                                        float* __restrict__ out) {
    __shared__ float rbuf[3][NN];
    __shared__ float y2s[MM];
    const int b = blockIdx.x;
    const int i = threadIdx.x;

    const float* xrow  = x + ((size_t)b * NN + i) * KK;
    const float* ybase = y + (size_t)b * MM * KK;

    float xr[KK];
    float x2 = 0.f;
#pragma unroll
    for (int k = 0; k < KK; k += 4) {
        const float4 v = *(const float4*)(xrow + k);
        xr[k] = v.x; xr[k + 1] = v.y; xr[k + 2] = v.z; xr[k + 3] = v.w;
        x2 = fmaf(v.x, v.x, fmaf(v.y, v.y, fmaf(v.z, v.z, fmaf(v.w, v.w, x2))));
    }
    {
        const float* yrow = ybase + (size_t)i * KK;
        float s = 0.f;
#pragma unroll
        for (int k = 0; k < KK; k += 4) {
            const float4 v = *(const float4*)(yrow + k);
            s = fmaf(v.x, v.x, s); s = fmaf(v.y, v.y, s);
            s = fmaf(v.z, v.z, s); s = fmaf(v.w, v.w, s);
        }
        y2s[i] = s;
    }
    rbuf[0][i] = LARGE_F;
    rbuf[1][i] = LARGE_F;
    rbuf[2][i] = LARGE_F;

    float* row_w  = rbuf[0];
    float* row_p  = rbuf[2];
    float* row_p2 = rbuf[1];
    __syncthreads();

    float cur = LARGE_F;
    for (int p = 0; p < NN + MM - 1; ++p) {
        const int j0 = p - i;
        const bool valid = (j0 >= 0) && (j0 < MM);
        float dg = 0.f;
        if (valid) {
            const float* yrow = ybase + (size_t)j0 * KK;
            float dot = 0.f;
#pragma unroll
            for (int k = 0; k < KK; k += 4) {
                const float4 v = *(const float4*)(yrow + k);
                dot = fmaf(xr[k], v.x, dot);
                dot = fmaf(xr[k + 1], v.y, dot);
                dot = fmaf(xr[k + 2], v.z, dot);
                dot = fmaf(xr[k + 3], v.w, dot);
            }
            dg = x2 + y2s[j0] - 2.f * dot;
        }
        const float r_w  = row_p[i];
        const float r_n  = (i > 0) ? row_p[i - 1] : LARGE_F;
        const float r_nw = (i > 0) ? row_p2[i - 1] : ((p == 0) ? 0.f : LARGE_F);

        const float m = fminf(fminf(r_nw, r_n), r_w);
        const float s = __expf(m - r_nw) + __expf(m - r_n) + __expf(m - r_w);
        const float softmin = m - __logf(s);

        cur = valid ? (dg + softmin) : LARGE_F;
        row_w[i] = cur;
        __syncthreads();

        float* tmp = row_w;
        row_w = row_p2; row_p2 = row_p; row_p = tmp;
    }
    if (i == NN - 1) out[b] = cur;
}

extern "C" void kernel_launch(void* const* d_in, const int* in_sizes, int n_in,
                              void* d_out, int out_size, void* d_ws, size_t ws_size,
                              hipStream_t stream) {
    const float* x = (const float*)d_in[0];
    const float* y = (const float*)d_in[1];
    float* out = (float*)d_out;

    if (ws_size >= NEED) {   // 67,244,032 B
        unsigned short* Dws = (unsigned short*)d_ws;
        sdtw_dist<<<dim3(2048), 256, 0, stream>>>(x, y, Dws);
        sdtw_dp<<<dim3(BB), 512, 0, stream>>>(Dws, out);
    } else {
        sdtw_fused_naive<<<dim3(BB), 512, 0, stream>>>(x, y, out);
    }
}